// Round 9
// baseline (13089.450 us; speedup 1.0000x reference)
//
#include <hip/hip_runtime.h>

#define S      4097              // states
#define KP     4160              // padded K: 130 blocks of 32; 520 uint4/row (mult of 8)
#define NBLK   256
#define NTHR   1024
#define VSTRIDE 4104             // value-buffer stride (floats, 16B-aligned)

typedef int   i32x4  __attribute__((ext_vector_type(4)));
typedef float f32x4  __attribute__((ext_vector_type(4)));
typedef short bf16x8 __attribute__((ext_vector_type(8)));

__device__ __forceinline__ float blo(unsigned int u) { return __uint_as_float(u << 16); }
__device__ __forceinline__ float bhi(unsigned int u) { return __uint_as_float(u & 0xffff0000u); }
__device__ __forceinline__ unsigned short rne_bf16(float x) {
  unsigned u = __float_as_uint(x);
  return (unsigned short)((u + 0x7fffu + ((u >> 16) & 1u)) >> 16);
}

__global__ void __launch_bounds__(NTHR) hmm_persist(
    const float* __restrict__ log_pi, const float* __restrict__ log_trans,
    const float* __restrict__ log_em, const int* __restrict__ obvs,
    int* __restrict__ tagbuf, float* __restrict__ valbuf, int T)
{
  __shared__ __align__(16) unsigned short plds[17 * KP];  // P^T bf16, XOR-swizzled rows
  __shared__ __align__(16) unsigned short vb[KP];         // v bf16 (linear)
  __shared__ __align__(16) float part[8][256];            // MFMA partials
  __shared__ float red[16];
  __shared__ float em_lds[17];
  __shared__ float part2[8];

  const int tid = threadIdx.x, lane = tid & 63, wid = tid >> 6;
  const int b = blockIdx.x, jb = b * 16;
  const int ncols = (b == NBLK - 1) ? 17 : 16;

  // ---- one-time: stage P^T tile as bf16, zero-padded to KP, XOR-swizzled:
  //      element (r,k) -> uint4 slot (k>>3)^(r&7) within row r ----
  for (int idx = tid; idx < ncols * KP; idx += NTHR) {
    int k = idx / ncols, r = idx - k * ncols;
    float p = (k < S) ? __expf(log_trans[(size_t)k * S + (jb + r)]) : 0.f;
    plds[r * KP + ((((k >> 3) ^ (r & 7)) << 3) | (k & 7))] = rne_bf16(p);
  }
  if (tid < KP - S) vb[S + tid] = 0;                      // static v padding
  __syncthreads();

  for (int t = 0; t < T; ++t) {
    const int    pi_in  = (t + 1) & 1;                    // buffer holding step t-1 (tags t)
    const int    pi_out = t & 1;
    const float* vin    = valbuf + pi_in * VSTRIDE;
    float*       vout   = valbuf + pi_out * VSTRIDE;
    const int*   tin    = tagbuf + pi_in * NBLK;
    int*         tout   = tagbuf + pi_out * NBLK;
    const int    obs    = obvs[t];

    // wave 15: issue em gather early (latency hides under the tag poll)
    float emv = 0.f;
    if (wid == 15 && lane < ncols) emv = log_em[(size_t)(jb + lane) * S + obs];

    // ---- detection: wave 0 polls the dense 256-tag array (1 KB/round) ----
    if (t > 0 && wid == 0) {
      const int* tp = tin + lane * 4;
      i32x4 Tg;
      for (;;) {
        asm volatile("global_load_dwordx4 %0, %1, off sc0 sc1"
                     : "=&v"(Tg) : "v"(tp) : "memory");
        asm volatile("s_waitcnt vmcnt(0)" ::: "memory");
        __builtin_amdgcn_sched_barrier(0);
        int mn = min(min(Tg.x, Tg.y), min(Tg.z, Tg.w));
        if (__all(mn >= t)) break;
        __builtin_amdgcn_s_sleep(2);
      }
    }
    __syncthreads();   // releases all waves once tags are fresh

    // ---- broadcast: all threads load the dense fp32 value vector (16 KB) ----
    float va0, va1, va2, va3, va4 = -3.4e38f;
    if (t == 0) {
      const float4 v4 = *(const float4*)(log_pi + 4 * tid);
      va0 = v4.x; va1 = v4.y; va2 = v4.z; va3 = v4.w;
      if (tid == 0) va4 = log_pi[4096];
    } else {
      f32x4 V; float V4 = -3.4e38f;
      const float* vp = vin + 4 * tid;
      asm volatile("global_load_dwordx4 %0, %1, off sc0 sc1"
                   : "=&v"(V) : "v"(vp) : "memory");
      if (tid == 0) {
        const float* v4p = vin + 4096;
        asm volatile("global_load_dword %0, %1, off sc0 sc1"
                     : "=&v"(V4) : "v"(v4p) : "memory");
      }
      asm volatile("s_waitcnt vmcnt(0)" ::: "memory");
      __builtin_amdgcn_sched_barrier(0);
      va0 = V.x; va1 = V.y; va2 = V.z; va3 = V.w;
      if (tid == 0) va4 = V4;
    }

    // block-wide max (red[lane&15] + shfl tree)
    float rmx = fmaxf(fmaxf(va0, va1), fmaxf(fmaxf(va2, va3), va4));
    #pragma unroll
    for (int off = 32; off; off >>= 1) rmx = fmaxf(rmx, __shfl_xor(rmx, off, 64));
    if (lane == 0) red[wid] = rmx;
    __syncthreads();
    float m = red[lane & 15];
    #pragma unroll
    for (int off = 8; off; off >>= 1) m = fmaxf(m, __shfl_xor(m, off, 64));

    // v = exp(va - m) -> bf16 (software RNE)
    float v0 = __expf(va0 - m), v1 = __expf(va1 - m);
    float v2 = __expf(va2 - m), v3 = __expf(va3 - m);
    unsigned b0 = rne_bf16(v0), b1 = rne_bf16(v1);
    unsigned b2 = rne_bf16(v2), b3 = rne_bf16(v3);
    *(int2*)(vb + 4 * tid) = make_int2((int)((b1 << 16) | b0), (int)((b3 << 16) | b2));
    if (tid == 0)
      *(int*)(vb + 4096) = (int)rne_bf16(__expf(va4 - m));  // [4096]=v4, [4097]=0
    if (wid == 15 && lane < ncols) em_lds[lane] = emv;
    __syncthreads();

    // ---- phase B: MFMA, A-read XOR-swizzled (conflict-free) ----
    if (wid < 8) {
      const int kb0 = wid * 16, kbn = (wid == 7) ? 17 : 16;   // 129 real K-blocks
      const int r = lane & 15, r7 = r & 7;
      const uint4* ap = ((const uint4*)plds) + r * (KP / 8);
      const uint4* vp = (const uint4*)vb;
      const int g = lane >> 4;
      f32x4 accA = {0.f, 0.f, 0.f, 0.f}, accB = {0.f, 0.f, 0.f, 0.f};
      for (int mm = kb0; mm + 1 < kb0 + kbn; mm += 2) {
        bf16x8 a0 = __builtin_bit_cast(bf16x8, ap[(mm * 4 + g) ^ r7]);
        bf16x8 w0 = __builtin_bit_cast(bf16x8, vp[mm * 4 + g]);
        accA = __builtin_amdgcn_mfma_f32_16x16x32_bf16(a0, w0, accA, 0, 0, 0);
        bf16x8 a1 = __builtin_bit_cast(bf16x8, ap[((mm + 1) * 4 + g) ^ r7]);
        bf16x8 w1 = __builtin_bit_cast(bf16x8, vp[(mm + 1) * 4 + g]);
        accB = __builtin_amdgcn_mfma_f32_16x16x32_bf16(a1, w1, accB, 0, 0, 0);
      }
      if (kbn & 1) {
        int mm = kb0 + kbn - 1;
        bf16x8 a0 = __builtin_bit_cast(bf16x8, ap[(mm * 4 + g) ^ r7]);
        bf16x8 w0 = __builtin_bit_cast(bf16x8, vp[mm * 4 + g]);
        accA = __builtin_amdgcn_mfma_f32_16x16x32_bf16(a0, w0, accA, 0, 0, 0);
      }
      accA += accB;
      *(f32x4*)&part[wid][lane * 4] = accA;
    } else if (b == NBLK - 1) {
      // waves 8-15: column 16 (state 4096). Row 16: 16&7==0 -> unswizzled, linear.
      float a16 = 0.f;
      const uint4* prow = (const uint4*)(plds + 16 * KP);
      const uint4* vp   = (const uint4*)vb;
      for (int ot = (wid - 8) * 64 + lane; ot < KP / 8; ot += 512) {
        uint4 pw = prow[ot], vw = vp[ot];
        a16 += blo(pw.x) * blo(vw.x) + bhi(pw.x) * bhi(vw.x);
        a16 += blo(pw.y) * blo(vw.y) + bhi(pw.y) * bhi(vw.y);
        a16 += blo(pw.z) * blo(vw.z) + bhi(pw.z) * bhi(vw.z);
        a16 += blo(pw.w) * blo(vw.w) + bhi(pw.w) * bhi(vw.w);
      }
      #pragma unroll
      for (int off = 32; off; off >>= 1) a16 += __shfl_xor(a16, off, 64);
      if (lane == 0) part2[wid - 8] = a16;
    }
    __syncthreads();

    // ---- finalize + publish (wave 15): values -> vmcnt(0) -> one tag dword ----
    if (wid == 15) {
      f32x4 tot = {0.f, 0.f, 0.f, 0.f};
      #pragma unroll
      for (int p = 0; p < 8; ++p) tot += *(const f32x4*)&part[p][lane * 4];
      if ((lane & 15) == 0) {                  // lanes 0,16,32,48: rows 4g..4g+3 (col 0)
        const int j0 = (lane >> 4) * 4;
        f32x4 o;
        o.x = em_lds[j0 + 0] + m + __logf(tot.x);
        o.y = em_lds[j0 + 1] + m + __logf(tot.y);
        o.z = em_lds[j0 + 2] + m + __logf(tot.z);
        o.w = em_lds[j0 + 3] + m + __logf(tot.w);
        const float* dst = vout + jb + j0;
        asm volatile("global_store_dwordx4 %0, %1, off sc0 sc1"
                     :: "v"(dst), "v"(o) : "memory");
      }
      if (b == NBLK - 1 && lane == 0) {
        float s16 = 0.f;
        #pragma unroll
        for (int p = 0; p < 8; ++p) s16 += part2[p];
        float r16 = em_lds[16] + m + __logf(s16);
        const float* dst = vout + 4096;
        asm volatile("global_store_dword %0, %1, off sc0 sc1"
                     :: "v"(dst), "v"(r16) : "memory");
      }
      asm volatile("s_waitcnt vmcnt(0)" ::: "memory");   // values at coherence point
      if (lane == 0) {
        const int tag = t + 1;
        const int* dst = tout + b;
        asm volatile("global_store_dword %0, %1, off sc0 sc1"
                     :: "v"(dst), "v"(tag) : "memory");
      }
    }
    __syncthreads();
  }
}

// termination: logsumexp_j(fs[j] + log_trans[j][0])
__global__ void __launch_bounds__(1024) hmm_final(
    const float* __restrict__ fs, const float* __restrict__ log_trans,
    float* __restrict__ out)
{
  __shared__ float red[16];
  const int tid = threadIdx.x, lane = tid & 63, wid = tid >> 6;
  float va[5];
  float rmax = -3.4e38f;
  #pragma unroll
  for (int i = 0; i < 5; ++i) {
    int k = tid + i * 1024;
    va[i] = (k < S) ? (fs[k] + log_trans[(size_t)k * S]) : -3.4e38f;
    rmax = fmaxf(rmax, va[i]);
  }
  #pragma unroll
  for (int off = 32; off; off >>= 1) rmax = fmaxf(rmax, __shfl_xor(rmax, off, 64));
  if (lane == 0) red[wid] = rmax;
  __syncthreads();
  float m = red[0];
  #pragma unroll
  for (int i = 1; i < 16; ++i) m = fmaxf(m, red[i]);
  float s = 0.f;
  #pragma unroll
  for (int i = 0; i < 5; ++i) s += __expf(va[i] - m);
  #pragma unroll
  for (int off = 32; off; off >>= 1) s += __shfl_xor(s, off, 64);
  __syncthreads();
  if (lane == 0) red[wid] = s;
  __syncthreads();
  if (tid == 0) {
    float tot = 0.f;
    #pragma unroll
    for (int i = 0; i < 16; ++i) tot += red[i];
    out[0] = m + __logf(tot);
  }
}

extern "C" void kernel_launch(void* const* d_in, const int* in_sizes, int n_in,
                              void* d_out, int out_size, void* d_ws, size_t ws_size,
                              hipStream_t stream) {
  const float* log_pi    = (const float*)d_in[0];
  const float* log_trans = (const float*)d_in[1];
  const float* log_em    = (const float*)d_in[2];
  const int*   obvs      = (const int*)d_in[3];
  const int    T         = in_sizes[3];

  int*   tags = (int*)d_ws;                          // 2 * 256 ints = 2 KB
  float* vals = (float*)((char*)d_ws + 2048);        // 2 * VSTRIDE floats

  hipMemsetAsync(tags, 0, 2048, stream);             // tags < 1: replay-safe
  hipLaunchKernelGGL(hmm_persist, dim3(NBLK), dim3(NTHR), 0, stream,
                     log_pi, log_trans, log_em, obvs, tags, vals, T);
  const float* fsT = vals + (size_t)((T - 1) & 1) * VSTRIDE;
  hipLaunchKernelGGL(hmm_final, dim3(1), dim3(1024), 0, stream,
                     fsT, log_trans, (float*)d_out);
}

// Round 10
// 7978.662 us; speedup vs baseline: 1.6406x; 1.6406x over previous
//
#include <hip/hip_runtime.h>

#define S       4097             // states
#define KP      4160             // padded K: 130 blocks of 32; 520 uint4/row (mult of 8)
#define NBLK    256
#define NTHR    1024
#define PSTRIDE 4104             // packed dwords per fs buffer (16B-aligned stride)

typedef int   i32x4  __attribute__((ext_vector_type(4)));
typedef float f32x4  __attribute__((ext_vector_type(4)));
typedef short bf16x8 __attribute__((ext_vector_type(8)));

__device__ __forceinline__ float blo(unsigned int u) { return __uint_as_float(u << 16); }
__device__ __forceinline__ float bhi(unsigned int u) { return __uint_as_float(u & 0xffff0000u); }
__device__ __forceinline__ unsigned short rne_bf16(float x) {
  unsigned u = __float_as_uint(x);
  return (unsigned short)((u + 0x7fffu + ((u >> 16) & 1u)) >> 16);
}

__global__ void __launch_bounds__(NTHR) hmm_persist(
    const float* __restrict__ log_pi, const float* __restrict__ log_trans,
    const float* __restrict__ log_em, const int* __restrict__ obvs,
    int* __restrict__ packs, float* __restrict__ basep, int T)
{
  __shared__ __align__(16) unsigned short plds[17 * KP];  // P^T bf16, XOR-swizzled rows
  __shared__ __align__(16) unsigned short vb[KP];         // v bf16 (linear)
  __shared__ __align__(16) float part[8][256];            // MFMA partials
  __shared__ float red[16];
  __shared__ float em_lds[17];
  __shared__ float part2[8];

  const int tid = threadIdx.x, lane = tid & 63, wid = tid >> 6;
  const int b = blockIdx.x, jb = b * 16;
  const int ncols = (b == NBLK - 1) ? 17 : 16;

  // ---- one-time: stage P^T tile as bf16, zero-padded to KP, XOR-swizzled:
  //      element (r,k) -> uint4 slot (k>>3)^(r&7) within row r ----
  for (int idx = tid; idx < ncols * KP; idx += NTHR) {
    int k = idx / ncols, r = idx - k * ncols;
    float p = (k < S) ? __expf(log_trans[(size_t)k * S + (jb + r)]) : 0.f;
    plds[r * KP + ((((k >> 3) ^ (r & 7)) << 3) | (k & 7))] = rne_bf16(p);
  }
  if (tid < KP - S) vb[S + tid] = 0;                      // static v padding
  float Bacc = 0.f;                                       // hidden base: identical per block
  __syncthreads();

  for (int t = 0; t < T; ++t) {
    const int* pin  = packs + ((t + 1) & 1) * PSTRIDE;    // tags == t when fresh
    int*       pout = packs + (t & 1) * PSTRIDE;
    const int  obs  = obvs[t];

    // wave 15: issue em gather early (latency hides under poll)
    float emv = 0.f;
    if (wid == 15 && lane < ncols) emv = log_em[(size_t)(jb + lane) * S + obs];

    // ---- phase A: fused barrier+broadcast — packed (bf16 D | tag16), 16 KB/round ----
    float va0, va1, va2, va3, va4 = -3.4e38f;
    if (t == 0) {
      const float4 v4 = *(const float4*)(log_pi + 4 * tid);
      va0 = v4.x; va1 = v4.y; va2 = v4.z; va3 = v4.w;
      if (tid == 0) va4 = log_pi[4096];
    } else {
      const int* pa = pin + 4 * tid;
      const int* pe = pin + 4096;
      i32x4 A; int E = 0;
      for (;;) {
        asm volatile("global_load_dwordx4 %0, %1, off sc0 sc1"
                     : "=&v"(A) : "v"(pa) : "memory");
        if (tid == 0)
          asm volatile("global_load_dword %0, %1, off sc0 sc1"
                       : "=&v"(E) : "v"(pe) : "memory");
        asm volatile("s_waitcnt vmcnt(0)" ::: "memory");
        __builtin_amdgcn_sched_barrier(0);
        bool ok = ((A.x & 0xffff) >= t) & ((A.y & 0xffff) >= t) &
                  ((A.z & 0xffff) >= t) & ((A.w & 0xffff) >= t);
        if (tid == 0) ok &= ((E & 0xffff) >= t);
        if (ok) {
          va0 = bhi(A.x); va1 = bhi(A.y); va2 = bhi(A.z); va3 = bhi(A.w);
          if (tid == 0) va4 = bhi(E);
          break;
        }
        __builtin_amdgcn_s_sleep(8);
      }
    }

    // block-wide max mD (order-invariant fmax over identical data -> bit-identical
    // across all blocks; folds into the hidden base, never communicated)
    float rmx = fmaxf(fmaxf(va0, va1), fmaxf(fmaxf(va2, va3), va4));
    #pragma unroll
    for (int off = 32; off; off >>= 1) rmx = fmaxf(rmx, __shfl_xor(rmx, off, 64));
    if (lane == 0) red[wid] = rmx;
    __syncthreads();
    float m = red[lane & 15];
    #pragma unroll
    for (int off = 8; off; off >>= 1) m = fmaxf(m, __shfl_xor(m, off, 64));
    Bacc += m;

    // v = exp(va - m) -> bf16 (software RNE)
    float v0 = __expf(va0 - m), v1 = __expf(va1 - m);
    float v2 = __expf(va2 - m), v3 = __expf(va3 - m);
    unsigned b0 = rne_bf16(v0), b1 = rne_bf16(v1);
    unsigned b2 = rne_bf16(v2), b3 = rne_bf16(v3);
    *(int2*)(vb + 4 * tid) = make_int2((int)((b1 << 16) | b0), (int)((b3 << 16) | b2));
    if (tid == 0)
      *(int*)(vb + 4096) = (int)rne_bf16(__expf(va4 - m));  // [4096]=v4, [4097]=0
    if (wid == 15 && lane < ncols) em_lds[lane] = emv;
    __syncthreads();

    // ---- phase B: MFMA, A-read XOR-swizzled (conflict-free) ----
    if (wid < 8) {
      const int kb0 = wid * 16, kbn = (wid == 7) ? 17 : 16;   // 129 real K-blocks
      const int r = lane & 15, r7 = r & 7;
      const uint4* ap = ((const uint4*)plds) + r * (KP / 8);
      const uint4* vp = (const uint4*)vb;
      const int g = lane >> 4;
      f32x4 accA = {0.f, 0.f, 0.f, 0.f}, accB = {0.f, 0.f, 0.f, 0.f};
      for (int mm = kb0; mm + 1 < kb0 + kbn; mm += 2) {
        bf16x8 a0 = __builtin_bit_cast(bf16x8, ap[(mm * 4 + g) ^ r7]);
        bf16x8 w0 = __builtin_bit_cast(bf16x8, vp[mm * 4 + g]);
        accA = __builtin_amdgcn_mfma_f32_16x16x32_bf16(a0, w0, accA, 0, 0, 0);
        bf16x8 a1 = __builtin_bit_cast(bf16x8, ap[((mm + 1) * 4 + g) ^ r7]);
        bf16x8 w1 = __builtin_bit_cast(bf16x8, vp[(mm + 1) * 4 + g]);
        accB = __builtin_amdgcn_mfma_f32_16x16x32_bf16(a1, w1, accB, 0, 0, 0);
      }
      if (kbn & 1) {
        int mm = kb0 + kbn - 1;
        bf16x8 a0 = __builtin_bit_cast(bf16x8, ap[(mm * 4 + g) ^ r7]);
        bf16x8 w0 = __builtin_bit_cast(bf16x8, vp[mm * 4 + g]);
        accA = __builtin_amdgcn_mfma_f32_16x16x32_bf16(a0, w0, accA, 0, 0, 0);
      }
      accA += accB;
      *(f32x4*)&part[wid][lane * 4] = accA;
    } else if (b == NBLK - 1) {
      // waves 8-15: column 16 (state 4096). Row 16: 16&7==0 -> unswizzled, linear.
      float a16 = 0.f;
      const uint4* prow = (const uint4*)(plds + 16 * KP);
      const uint4* vp   = (const uint4*)vb;
      for (int ot = (wid - 8) * 64 + lane; ot < KP / 8; ot += 512) {
        uint4 pw = prow[ot], vw = vp[ot];
        a16 += blo(pw.x) * blo(vw.x) + bhi(pw.x) * bhi(vw.x);
        a16 += blo(pw.y) * blo(vw.y) + bhi(pw.y) * bhi(vw.y);
        a16 += blo(pw.z) * blo(vw.z) + bhi(pw.z) * bhi(vw.z);
        a16 += blo(pw.w) * blo(vw.w) + bhi(pw.w) * bhi(vw.w);
      }
      #pragma unroll
      for (int off = 32; off; off >>= 1) a16 += __shfl_xor(a16, off, 64);
      if (lane == 0) part2[wid - 8] = a16;
    }
    __syncthreads();

    // ---- finalize + publish (wave 15): D_new = em + log(dot); base absorbs m ----
    const int tag = t + 1;
    if (wid == 15) {
      f32x4 tot = {0.f, 0.f, 0.f, 0.f};
      #pragma unroll
      for (int p = 0; p < 8; ++p) tot += *(const f32x4*)&part[p][lane * 4];
      if ((lane & 15) == 0) {                  // lanes 0,16,32,48: rows 4g..4g+3 (col 0)
        const int j0 = (lane >> 4) * 4;
        float d0 = em_lds[j0 + 0] + __logf(tot.x);
        float d1 = em_lds[j0 + 1] + __logf(tot.y);
        float d2 = em_lds[j0 + 2] + __logf(tot.z);
        float d3 = em_lds[j0 + 3] + __logf(tot.w);
        i32x4 o;
        o.x = ((int)rne_bf16(d0) << 16) | tag;
        o.y = ((int)rne_bf16(d1) << 16) | tag;
        o.z = ((int)rne_bf16(d2) << 16) | tag;
        o.w = ((int)rne_bf16(d3) << 16) | tag;
        const int* dst = pout + jb + j0;
        asm volatile("global_store_dwordx4 %0, %1, off sc0 sc1"
                     :: "v"(dst), "v"(o) : "memory");
      }
      if (b == NBLK - 1 && lane == 0) {
        float s16 = 0.f;
        #pragma unroll
        for (int p = 0; p < 8; ++p) s16 += part2[p];
        float d16 = em_lds[16] + __logf(s16);
        int o16 = ((int)rne_bf16(d16) << 16) | tag;
        const int* dst = pout + 4096;
        asm volatile("global_store_dword %0, %1, off sc0 sc1"
                     :: "v"(dst), "v"(o16) : "memory");
      }
    }
    __syncthreads();
  }
  if (b == 0 && tid == 0) basep[0] = Bacc;   // kernel-end flush makes this visible
}

// termination: B + logsumexp_j(D[j] + log_trans[j][0])
__global__ void __launch_bounds__(1024) hmm_final(
    const int* __restrict__ dq, const float* __restrict__ log_trans,
    const float* __restrict__ basep, float* __restrict__ out)
{
  __shared__ float red[16];
  const int tid = threadIdx.x, lane = tid & 63, wid = tid >> 6;
  float va[5];
  float rmax = -3.4e38f;
  #pragma unroll
  for (int i = 0; i < 5; ++i) {
    int k = tid + i * 1024;
    va[i] = (k < S) ? (bhi(dq[k]) + log_trans[(size_t)k * S]) : -3.4e38f;
    rmax = fmaxf(rmax, va[i]);
  }
  #pragma unroll
  for (int off = 32; off; off >>= 1) rmax = fmaxf(rmax, __shfl_xor(rmax, off, 64));
  if (lane == 0) red[wid] = rmax;
  __syncthreads();
  float m = red[0];
  #pragma unroll
  for (int i = 1; i < 16; ++i) m = fmaxf(m, red[i]);
  float s = 0.f;
  #pragma unroll
  for (int i = 0; i < 5; ++i) s += __expf(va[i] - m);
  #pragma unroll
  for (int off = 32; off; off >>= 1) s += __shfl_xor(s, off, 64);
  __syncthreads();
  if (lane == 0) red[wid] = s;
  __syncthreads();
  if (tid == 0) {
    float tot = 0.f;
    #pragma unroll
    for (int i = 0; i < 16; ++i) tot += red[i];
    out[0] = basep[0] + m + __logf(tot);
  }
}

extern "C" void kernel_launch(void* const* d_in, const int* in_sizes, int n_in,
                              void* d_out, int out_size, void* d_ws, size_t ws_size,
                              hipStream_t stream) {
  const float* log_pi    = (const float*)d_in[0];
  const float* log_trans = (const float*)d_in[1];
  const float* log_em    = (const float*)d_in[2];
  const int*   obvs      = (const int*)d_in[3];
  const int    T         = in_sizes[3];

  int*   packs = (int*)d_ws;                             // 2 * PSTRIDE dwords
  float* basep = (float*)((char*)d_ws + 2 * PSTRIDE * 4);

  hipMemsetAsync(packs, 0, 2 * PSTRIDE * 4, stream);     // tags < 1: replay-safe
  hipLaunchKernelGGL(hmm_persist, dim3(NBLK), dim3(NTHR), 0, stream,
                     log_pi, log_trans, log_em, obvs, packs, basep, T);
  const int* fsT = packs + (size_t)((T - 1) & 1) * PSTRIDE;
  hipLaunchKernelGGL(hmm_final, dim3(1), dim3(1024), 0, stream,
                     fsT, log_trans, basep, (float*)d_out);
}

// Round 11
// 5685.343 us; speedup vs baseline: 2.3023x; 1.4034x over previous
//
#include <hip/hip_runtime.h>

#define S       4097             // states
#define KP      4160             // padded K: 130 blocks of 32; 520 uint4/row (mult of 8)
#define NBLK    256
#define NTHR    1024
#define PSTRIDE 4104             // packed dwords per fs buffer (16B-aligned stride)

typedef int   i32x4  __attribute__((ext_vector_type(4)));
typedef float f32x4  __attribute__((ext_vector_type(4)));
typedef short bf16x8 __attribute__((ext_vector_type(8)));

__device__ __forceinline__ float blo(unsigned int u) { return __uint_as_float(u << 16); }
__device__ __forceinline__ float bhi(unsigned int u) { return __uint_as_float(u & 0xffff0000u); }
__device__ __forceinline__ unsigned short rne_bf16(float x) {
  unsigned u = __float_as_uint(x);
  return (unsigned short)((u + 0x7fffu + ((u >> 16) & 1u)) >> 16);
}

__global__ void __launch_bounds__(NTHR) hmm_persist(
    const float* __restrict__ log_pi, const float* __restrict__ log_trans,
    const float* __restrict__ log_em, const int* __restrict__ obvs,
    int* __restrict__ packs, float* __restrict__ basep, int T)
{
  __shared__ __align__(16) unsigned short plds[17 * KP];  // P^T bf16, XOR-swizzled rows
  __shared__ __align__(16) unsigned short vb[KP];         // v bf16 (linear)
  __shared__ __align__(16) float part[8][256];            // MFMA partials
  __shared__ float red[16];                               // per-wave maxima (for NEXT step)
  __shared__ float em_lds[17];
  __shared__ float part2[8];

  const int tid = threadIdx.x, lane = tid & 63, wid = tid >> 6;
  const int b = blockIdx.x, jb = b * 16;
  const int ncols = (b == NBLK - 1) ? 17 : 16;

  // ---- one-time: stage P^T tile as bf16, zero-padded to KP, XOR-swizzled ----
  for (int idx = tid; idx < ncols * KP; idx += NTHR) {
    int k = idx / ncols, r = idx - k * ncols;
    float p = (k < S) ? __expf(log_trans[(size_t)k * S + (jb + r)]) : 0.f;
    plds[r * KP + ((((k >> 3) ^ (r & 7)) << 3) | (k & 7))] = rne_bf16(p);
  }
  if (tid < KP - S) vb[S + tid] = 0;                      // static v padding
  float Bacc = 0.f;                                       // hidden base (identical per block)
  float s    = 0.f;                                       // lagged shift, s_0 = 0
  __syncthreads();

  // ---- persistent A-fragment preload: P is immutable, hold first 8 K-blocks in regs ----
  const int   kb0 = (wid & 7) * 16;
  const int   rr  = lane & 15, r7 = rr & 7;
  const int   g   = lane >> 4;
  const uint4* ap = ((const uint4*)plds) + rr * (KP / 8);
  const uint4* vp = (const uint4*)vb;
  bf16x8 pre[8];
  #pragma unroll
  for (int i = 0; i < 8; ++i)
    pre[i] = __builtin_bit_cast(bf16x8, ap[((kb0 + i) * 4 + g) ^ r7]);  // wid>=8: benign reads

  for (int t = 0; t < T; ++t) {
    const int* pin  = packs + ((t + 1) & 1) * PSTRIDE;    // tags == t when fresh
    int*       pout = packs + (t & 1) * PSTRIDE;
    const int  obs  = obvs[t];

    // combine last step's per-wave maxima into this step's shift (off critical reduce)
    if (t > 0) {
      float mn = red[lane & 15];
      #pragma unroll
      for (int off = 8; off; off >>= 1) mn = fmaxf(mn, __shfl_xor(mn, off, 64));
      s = mn;
    }
    Bacc += s;

    // wave 15: issue em gather early (latency hides under poll)
    float emv = 0.f;
    if (wid == 15 && lane < ncols) emv = log_em[(size_t)(jb + lane) * S + obs];

    // ---- phase A: fused barrier+broadcast — packed (bf16 D | tag16) ----
    float va0, va1, va2, va3, va4 = -3.4e38f;
    if (t == 0) {
      const float4 v4 = *(const float4*)(log_pi + 4 * tid);
      va0 = v4.x; va1 = v4.y; va2 = v4.z; va3 = v4.w;
      if (tid == 0) va4 = log_pi[4096];
    } else {
      const int* pa = pin + 4 * tid;
      const int* pe = pin + 4096;
      i32x4 A; int E = 0;
      for (;;) {
        asm volatile("global_load_dwordx4 %0, %1, off sc0 sc1"
                     : "=&v"(A) : "v"(pa) : "memory");
        if (tid == 0)
          asm volatile("global_load_dword %0, %1, off sc0 sc1"
                       : "=&v"(E) : "v"(pe) : "memory");
        asm volatile("s_waitcnt vmcnt(0)" ::: "memory");
        __builtin_amdgcn_sched_barrier(0);
        bool ok = ((A.x & 0xffff) >= t) & ((A.y & 0xffff) >= t) &
                  ((A.z & 0xffff) >= t) & ((A.w & 0xffff) >= t);
        if (tid == 0) ok &= ((E & 0xffff) >= t);
        if (ok) {
          va0 = bhi(A.x); va1 = bhi(A.y); va2 = bhi(A.z); va3 = bhi(A.w);
          if (tid == 0) va4 = bhi(E);
          break;
        }
        __builtin_amdgcn_s_sleep(1);
      }
    }

    // v = exp(va - s) -> bf16; lagged shift keeps args within +/- a few (overflow-safe)
    float v0 = __expf(va0 - s), v1 = __expf(va1 - s);
    float v2 = __expf(va2 - s), v3 = __expf(va3 - s);
    unsigned b0 = rne_bf16(v0), b1 = rne_bf16(v1);
    unsigned b2 = rne_bf16(v2), b3 = rne_bf16(v3);
    *(int2*)(vb + 4 * tid) = make_int2((int)((b1 << 16) | b0), (int)((b3 << 16) | b2));
    if (tid == 0)
      *(int*)(vb + 4096) = (int)rne_bf16(__expf(va4 - s));  // [4096]=v4, [4097]=0
    if (wid == 15 && lane < ncols) em_lds[lane] = emv;

    // per-wave max of loaded data -> red[] (consumed NEXT step; identical on all blocks)
    float rmx = fmaxf(fmaxf(va0, va1), fmaxf(fmaxf(va2, va3), va4));
    #pragma unroll
    for (int off = 32; off; off >>= 1) rmx = fmaxf(rmx, __shfl_xor(rmx, off, 64));
    if (lane == 0) red[wid] = rmx;
    __syncthreads();

    // ---- phase B: MFMA; first 8 K-blocks from persistent regs, rest ds_read ----
    if (wid < 8) {
      const int kbn = (wid == 7) ? 17 : 16;               // 129 real K-blocks
      f32x4 accA = {0.f, 0.f, 0.f, 0.f}, accB = {0.f, 0.f, 0.f, 0.f};
      #pragma unroll
      for (int i = 0; i < 8; i += 2) {
        bf16x8 w0 = __builtin_bit_cast(bf16x8, vp[(kb0 + i) * 4 + g]);
        accA = __builtin_amdgcn_mfma_f32_16x16x32_bf16(pre[i], w0, accA, 0, 0, 0);
        bf16x8 w1 = __builtin_bit_cast(bf16x8, vp[(kb0 + i + 1) * 4 + g]);
        accB = __builtin_amdgcn_mfma_f32_16x16x32_bf16(pre[i + 1], w1, accB, 0, 0, 0);
      }
      for (int mm = kb0 + 8; mm + 1 < kb0 + kbn; mm += 2) {
        bf16x8 a0 = __builtin_bit_cast(bf16x8, ap[(mm * 4 + g) ^ r7]);
        bf16x8 w0 = __builtin_bit_cast(bf16x8, vp[mm * 4 + g]);
        accA = __builtin_amdgcn_mfma_f32_16x16x32_bf16(a0, w0, accA, 0, 0, 0);
        bf16x8 a1 = __builtin_bit_cast(bf16x8, ap[((mm + 1) * 4 + g) ^ r7]);
        bf16x8 w1 = __builtin_bit_cast(bf16x8, vp[(mm + 1) * 4 + g]);
        accB = __builtin_amdgcn_mfma_f32_16x16x32_bf16(a1, w1, accB, 0, 0, 0);
      }
      if (kbn & 1) {
        int mm = kb0 + kbn - 1;
        bf16x8 a0 = __builtin_bit_cast(bf16x8, ap[(mm * 4 + g) ^ r7]);
        bf16x8 w0 = __builtin_bit_cast(bf16x8, vp[mm * 4 + g]);
        accA = __builtin_amdgcn_mfma_f32_16x16x32_bf16(a0, w0, accA, 0, 0, 0);
      }
      accA += accB;
      *(f32x4*)&part[wid][lane * 4] = accA;
    } else if (b == NBLK - 1) {
      // waves 8-15: column 16 (state 4096). Row 16: 16&7==0 -> unswizzled, linear.
      float a16 = 0.f;
      const uint4* prow = (const uint4*)(plds + 16 * KP);
      for (int ot = (wid - 8) * 64 + lane; ot < KP / 8; ot += 512) {
        uint4 pw = prow[ot], vw = vp[ot];
        a16 += blo(pw.x) * blo(vw.x) + bhi(pw.x) * bhi(vw.x);
        a16 += blo(pw.y) * blo(vw.y) + bhi(pw.y) * bhi(vw.y);
        a16 += blo(pw.z) * blo(vw.z) + bhi(pw.z) * bhi(vw.z);
        a16 += blo(pw.w) * blo(vw.w) + bhi(pw.w) * bhi(vw.w);
      }
      #pragma unroll
      for (int off = 32; off; off >>= 1) a16 += __shfl_xor(a16, off, 64);
      if (lane == 0) part2[wid - 8] = a16;
    }
    __syncthreads();

    // ---- finalize + publish (wave 15): D_new = em + log(dot); base absorbs s ----
    const int tag = t + 1;
    if (wid == 15) {
      f32x4 tot = {0.f, 0.f, 0.f, 0.f};
      #pragma unroll
      for (int p = 0; p < 8; ++p) tot += *(const f32x4*)&part[p][lane * 4];
      if ((lane & 15) == 0) {                  // lanes 0,16,32,48: rows 4g..4g+3 (col 0)
        const int j0 = (lane >> 4) * 4;
        float d0 = em_lds[j0 + 0] + __logf(tot.x);
        float d1 = em_lds[j0 + 1] + __logf(tot.y);
        float d2 = em_lds[j0 + 2] + __logf(tot.z);
        float d3 = em_lds[j0 + 3] + __logf(tot.w);
        i32x4 o;
        o.x = ((int)rne_bf16(d0) << 16) | tag;
        o.y = ((int)rne_bf16(d1) << 16) | tag;
        o.z = ((int)rne_bf16(d2) << 16) | tag;
        o.w = ((int)rne_bf16(d3) << 16) | tag;
        const int* dst = pout + jb + j0;
        asm volatile("global_store_dwordx4 %0, %1, off sc0 sc1"
                     :: "v"(dst), "v"(o) : "memory");
      }
      if (b == NBLK - 1 && lane == 0) {
        float s16 = 0.f;
        #pragma unroll
        for (int p = 0; p < 8; ++p) s16 += part2[p];
        float d16 = em_lds[16] + __logf(s16);
        int o16 = ((int)rne_bf16(d16) << 16) | tag;
        const int* dst = pout + 4096;
        asm volatile("global_store_dword %0, %1, off sc0 sc1"
                     :: "v"(dst), "v"(o16) : "memory");
      }
    }
    __syncthreads();
  }
  if (b == 0 && tid == 0) basep[0] = Bacc;   // kernel-end flush makes this visible
}

// termination: B + logsumexp_j(D[j] + log_trans[j][0])
__global__ void __launch_bounds__(1024) hmm_final(
    const int* __restrict__ dq, const float* __restrict__ log_trans,
    const float* __restrict__ basep, float* __restrict__ out)
{
  __shared__ float red[16];
  const int tid = threadIdx.x, lane = tid & 63, wid = tid >> 6;
  float va[5];
  float rmax = -3.4e38f;
  #pragma unroll
  for (int i = 0; i < 5; ++i) {
    int k = tid + i * 1024;
    va[i] = (k < S) ? (bhi(dq[k]) + log_trans[(size_t)k * S]) : -3.4e38f;
    rmax = fmaxf(rmax, va[i]);
  }
  #pragma unroll
  for (int off = 32; off; off >>= 1) rmax = fmaxf(rmax, __shfl_xor(rmax, off, 64));
  if (lane == 0) red[wid] = rmax;
  __syncthreads();
  float m = red[0];
  #pragma unroll
  for (int i = 1; i < 16; ++i) m = fmaxf(m, red[i]);
  float s = 0.f;
  #pragma unroll
  for (int i = 0; i < 5; ++i) s += __expf(va[i] - m);
  #pragma unroll
  for (int off = 32; off; off >>= 1) s += __shfl_xor(s, off, 64);
  __syncthreads();
  if (lane == 0) red[wid] = s;
  __syncthreads();
  if (tid == 0) {
    float tot = 0.f;
    #pragma unroll
    for (int i = 0; i < 16; ++i) tot += red[i];
    out[0] = basep[0] + m + __logf(tot);
  }
}

extern "C" void kernel_launch(void* const* d_in, const int* in_sizes, int n_in,
                              void* d_out, int out_size, void* d_ws, size_t ws_size,
                              hipStream_t stream) {
  const float* log_pi    = (const float*)d_in[0];
  const float* log_trans = (const float*)d_in[1];
  const float* log_em    = (const float*)d_in[2];
  const int*   obvs      = (const int*)d_in[3];
  const int    T         = in_sizes[3];

  int*   packs = (int*)d_ws;                             // 2 * PSTRIDE dwords
  float* basep = (float*)((char*)d_ws + 2 * PSTRIDE * 4);

  hipMemsetAsync(packs, 0, 2 * PSTRIDE * 4, stream);     // tags < 1: replay-safe
  hipLaunchKernelGGL(hmm_persist, dim3(NBLK), dim3(NTHR), 0, stream,
                     log_pi, log_trans, log_em, obvs, packs, basep, T);
  const int* fsT = packs + (size_t)((T - 1) & 1) * PSTRIDE;
  hipLaunchKernelGGL(hmm_final, dim3(1), dim3(1024), 0, stream,
                     fsT, log_trans, basep, (float*)d_out);
}